// Round 7
// baseline (161.327 us; speedup 1.0000x reference)
//
#include <hip/hip_runtime.h>
#include <stdint.h>

typedef unsigned short u16;
typedef short short8 __attribute__((ext_vector_type(8)));
typedef float f32x4 __attribute__((ext_vector_type(4)));
typedef float f32x16 __attribute__((ext_vector_type(16)));
typedef unsigned int uint2v __attribute__((ext_vector_type(2)));

#define K2E 0.18033688011112042f  /* 0.125 * log2(e) */

__device__ __forceinline__ u16 f2bf(float f) {
  union { float f; uint32_t u; } v;
  v.f = f;
  uint32_t u = v.u;
  u += 0x7FFFu + ((u >> 16) & 1u);
  return (u16)(u >> 16);
}

__device__ __forceinline__ uint32_t cvtpk(float lo, float hi) {
  uint32_t r;
  asm("v_cvt_pk_bf16_f32 %0, %1, %2" : "=v"(r) : "v"(lo), "v"(hi));
  return r;
}

__device__ __forceinline__ float exp2a(float x) {
  float r;
  asm("v_exp_f32 %0, %1" : "=v"(r) : "v"(x));
  return r;
}

__device__ __forceinline__ float mask_zero(float p, uint32_t zm, int oc) {
  int mext = __builtin_amdgcn_sbfe((int)zm, oc, 1);
  float r;
  asm("v_bfi_b32 %0, %1, 0, %2" : "=v"(r) : "v"(mext), "v"(p));
  return r;
}

__device__ __forceinline__ void gld_lds16(const u16* src, char* dst) {
  __builtin_amdgcn_global_load_lds((const __attribute__((address_space(1))) void*)src,
                                   (__attribute__((address_space(3))) void*)dst, 16, 0, 0);
}

__device__ __forceinline__ void pack_frags(const f32x16& v, short8& fa, short8& fb) {
  union U { uint32_t w[4]; short8 v8; };
  uint32_t X0 = cvtpk(v[0], v[1]),   X1 = cvtpk(v[2], v[3]);
  uint32_t Y0 = cvtpk(v[4], v[5]),   Y1 = cvtpk(v[6], v[7]);
  uint32_t X2 = cvtpk(v[8], v[9]),   X3 = cvtpk(v[10], v[11]);
  uint32_t Y2 = cvtpk(v[12], v[13]), Y3 = cvtpk(v[14], v[15]);
  uint2v r0 = __builtin_amdgcn_permlane32_swap(X0, Y0, false, false);
  uint2v r1 = __builtin_amdgcn_permlane32_swap(X1, Y1, false, false);
  uint2v r2 = __builtin_amdgcn_permlane32_swap(X2, Y2, false, false);
  uint2v r3 = __builtin_amdgcn_permlane32_swap(X3, Y3, false, false);
  U ua; ua.w[0] = r0.x; ua.w[1] = r1.x; ua.w[2] = r0.y; ua.w[3] = r1.y; fa = ua.v8;
  U ub; ub.w[0] = r2.x; ub.w[1] = r3.x; ub.w[2] = r2.y; ub.w[3] = r3.y; fb = ub.v8;
}

// ---------------- prep kernels ----------------

__global__ __launch_bounds__(256) void k_cvt_x(const float* __restrict__ x,
                                               u16* __restrict__ xb, int n4) {
  int g = blockIdx.x * 256 + threadIdx.x;
  if (g >= n4) return;
  float4 v = ((const float4*)x)[g];
  ushort4 o;
  o.x = f2bf(v.x); o.y = f2bf(v.y); o.z = f2bf(v.z); o.w = f2bf(v.w);
  ((ushort4*)xb)[g] = o;
}

__global__ __launch_bounds__(256) void k_transpose_bf(const float* __restrict__ src,
                                                      u16* __restrict__ dst, int R, int C) {
  __shared__ float t[32][33];
  int c0 = blockIdx.x * 32, r0 = blockIdx.y * 32;
  int tx = threadIdx.x, ty = threadIdx.y;
#pragma unroll
  for (int i = 0; i < 4; ++i)
    t[ty + 8 * i][tx] = src[(size_t)(r0 + ty + 8 * i) * C + c0 + tx];
  __syncthreads();
#pragma unroll
  for (int i = 0; i < 4; ++i)
    dst[(size_t)(c0 + ty + 8 * i) * R + r0 + tx] = f2bf(t[tx][ty + 8 * i]);
}

__global__ __launch_bounds__(256) void k_mask_pack(const int* __restrict__ m,
                                                   uint32_t* __restrict__ w, int n) {
  int g = blockIdx.x * 256 + threadIdx.x;
  if (g >= n) return;
  unsigned long long bal = __ballot(m[g] != 0);
  int lane = threadIdx.x & 63;
  if (lane == 0) w[g >> 5] = (uint32_t)bal;
  else if (lane == 32) w[g >> 5] = (uint32_t)(bal >> 32);
}

// ---------------- GEMM 256x256 8-phase core (qkv) ----------------
// BM=BN=256, BK=64, 512 thr = 8 waves (2M x 4N). LDS 128KB:
// buf(2) x [A0 16K | A1 16K | B0 16K | B1 16K]; half = [128 rows][64 k] bf16,
// st_16x32 swizzle: chunk c of row r stored at c ^ (((r>>2)&1)<<1)  (m201).
// Staged both-sides: pre-swizzled global source (full 128B lines), swizzled read.
// Per K-tile: 4 quadrant phases; stage A(t+1) at ph0 (+vmcnt(4)), B(t+1) at ph1.
// Main loop never drains vmcnt to 0 (T4); setprio around MFMA (T5).

#define GQ_STAGE_A(T1)                                             \
  {                                                                \
    const size_t k0_ = (size_t)(T1) << 6;                          \
    char* bb_ = lds + (((T1) & 1) << 16) + (w << 10);              \
    const u16* s_ = pA + w8K + k0_;                                \
    gld_lds16(s_, bb_);                                            \
    gld_lds16(s_ + 64 * (size_t)GQK, bb_ + 8192);                  \
    gld_lds16(s_ + 128 * (size_t)GQK, bb_ + 16384);                \
    gld_lds16(s_ + 192 * (size_t)GQK, bb_ + 24576);                \
  }
#define GQ_STAGE_B(T1)                                             \
  {                                                                \
    const size_t k0_ = (size_t)(T1) << 6;                          \
    char* bb_ = lds + (((T1) & 1) << 16) + 32768 + (w << 10);      \
    const u16* s_ = pB + w8K + k0_;                                \
    gld_lds16(s_, bb_);                                            \
    gld_lds16(s_ + 64 * (size_t)GQK, bb_ + 8192);                  \
    gld_lds16(s_ + 128 * (size_t)GQK, bb_ + 16384);                \
    gld_lds16(s_ + 192 * (size_t)GQK, bb_ + 24576);                \
  }

#define GQ_RD_AF(MQ)                                               \
  _Pragma("unroll")                                                \
  for (int j = 0; j < 4; ++j) {                                    \
    const char* ra_ = aB + ((MQ) * 64 + j * 16 + lr) * 128;        \
    af[j][0] = *(const short8*)(ra_ + cof0);                       \
    af[j][1] = *(const short8*)(ra_ + cof1);                       \
  }
#define GQ_RD_BF(NH)                                               \
  _Pragma("unroll")                                                \
  for (int nn = 0; nn < 2; ++nn) {                                 \
    const char* rb_ = bB + (wn1 * 64 + ((NH) * 2 + nn) * 16 + lr) * 128; \
    bfr[nn][0] = *(const short8*)(rb_ + cof0);                     \
    bfr[nn][1] = *(const short8*)(rb_ + cof1);                     \
  }

#define GQ_MFMA(MQ, NH)                                            \
  __builtin_amdgcn_s_setprio(1);                                   \
  _Pragma("unroll")                                                \
  for (int j = 0; j < 4; ++j)                                      \
    _Pragma("unroll")                                              \
    for (int nn = 0; nn < 2; ++nn) {                               \
      acc[(MQ) * 4 + j][(NH) * 2 + nn] = __builtin_amdgcn_mfma_f32_16x16x32_bf16( \
          af[j][0], bfr[nn][0], acc[(MQ) * 4 + j][(NH) * 2 + nn], 0, 0, 0);        \
      acc[(MQ) * 4 + j][(NH) * 2 + nn] = __builtin_amdgcn_mfma_f32_16x16x32_bf16( \
          af[j][1], bfr[nn][1], acc[(MQ) * 4 + j][(NH) * 2 + nn], 0, 0, 0);        \
    }                                                              \
  __builtin_amdgcn_s_setprio(0);

#define GQ_LGKM                                                     \
  asm volatile("s_waitcnt lgkmcnt(0)" ::: "memory");                \
  __builtin_amdgcn_sched_barrier(0);
#define GQ_BAR __builtin_amdgcn_s_barrier();

#define GQK 1024

__global__ __launch_bounds__(512, 2) void k_gemm_qkv(const u16* __restrict__ A,
                                                     const u16* __restrict__ Bt,
                                                     u16* __restrict__ Qb,
                                                     u16* __restrict__ Kb,
                                                     u16* __restrict__ VT) {
  __shared__ char lds[131072] __attribute__((aligned(128)));
  const int n0 = blockIdx.x * 256, m0 = blockIdx.y * 256;
  const int t = threadIdx.x;
  const int l = t & 63, w = t >> 6;
  const int wm = w >> 2, wn = w & 3;
  const int wn1 = wn & 1;
  const int lr = l & 15, lg = l >> 4;
  const int swl = ((lr >> 2) & 1) << 1;
  const int cof0 = ((lg ^ swl) << 4);
  const int cof1 = cof0 + 64;

  // staging per-lane source (pre-swizzled chunk; full 128B lines per 8-row group)
  const int d3l = l >> 3;
  const int cse = ((l & 7) ^ (((l >> 5) & 1) << 1)) << 3;  // elems
  const u16* pA = A + (size_t)(m0 + d3l) * GQK + cse;
  const u16* pB = Bt + (size_t)(n0 + d3l) * GQK + cse;
  const size_t w8K = (size_t)(8 * w) * GQK;

  f32x4 acc[8][4] = {};
  short8 af[4][2], bfr[2][2];

  // prologue: stage tile 0 fully
  GQ_STAGE_A(0);
  GQ_STAGE_B(0);

#pragma unroll 1
  for (int tt = 0; tt < 16; ++tt) {
    const char* aB = lds + ((tt & 1) << 16) + wm * 16384;
    const char* bB = lds + ((tt & 1) << 16) + 32768 + (wn >> 1) * 16384;
    // ---- ph0: (mq0, nh0) ----
    if (tt < 15) {
      GQ_STAGE_A(tt + 1);
      asm volatile("s_waitcnt vmcnt(4)" ::: "memory");
    } else {
      asm volatile("s_waitcnt vmcnt(0)" ::: "memory");
    }
    __builtin_amdgcn_sched_barrier(0);
    GQ_BAR
    GQ_RD_AF(0)
    GQ_RD_BF(0)
    GQ_LGKM
    GQ_MFMA(0, 0)
    GQ_BAR
    // ---- ph1: (mq1, nh0) ----
    if (tt < 15) GQ_STAGE_B(tt + 1);
    GQ_RD_AF(1)
    GQ_BAR
    GQ_LGKM
    GQ_MFMA(1, 0)
    GQ_BAR
    // ---- ph2: (mq1, nh1) ----
    GQ_RD_BF(1)
    GQ_BAR
    GQ_LGKM
    GQ_MFMA(1, 1)
    GQ_BAR
    // ---- ph3: (mq0, nh1) ----
    GQ_RD_AF(0)
    GQ_BAR
    GQ_LGKM
    GQ_MFMA(0, 1)
    GQ_BAR
  }

  // epilogue: scatter into Q (pre-scaled by K2E), K, V^T
#pragma unroll
  for (int mi = 0; mi < 8; ++mi)
#pragma unroll
    for (int ni = 0; ni < 4; ++ni)
#pragma unroll
      for (int r = 0; r < 4; ++r) {
        int m = m0 + wm * 128 + mi * 16 + lg * 4 + r;
        int n = n0 + wn * 64 + ni * 16 + lr;
        int b = m >> 11, seq = m & 2047;
        float av = acc[mi][ni][r];
        if (n < 1024) {
          Qb[((size_t)((b << 4) + (n >> 6)) * 2048 + seq) * 64 + (n & 63)] = f2bf(av * K2E);
        } else if (n < 2048) {
          int nn = n - 1024;
          Kb[((size_t)((b << 4) + (nn >> 6)) * 2048 + seq) * 64 + (nn & 63)] = f2bf(av);
        } else {
          int nn = n - 2048;
          VT[((size_t)((b << 4) + (nn >> 6)) * 64 + (nn & 63)) * 2048 + seq] = f2bf(av);
        }
      }
}

// ---------------- GEMM 128x128 3-ring core (gemm_out, unchanged from R6) ----------------

#define GS(U, BUF)                                                   \
  {                                                                  \
    char* dA_ = lds + (BUF) * 16384 + (w << 11);                     \
    const u16* a_ = As + ((U) << 5);                                 \
    const u16* b_ = Bs + ((U) << 5);                                 \
    gld_lds16(a_, dA_);                                              \
    gld_lds16(a_ + (K << 4), dA_ + 1024);                            \
    gld_lds16(b_, dA_ + 8192);                                       \
    gld_lds16(b_ + (K << 4), dA_ + 9216);                            \
  }

#define PH(U, BUF, DOSTAGE, VMS)                                                          \
  {                                                                                       \
    asm volatile("s_waitcnt vmcnt(" VMS ")" ::: "memory");                                \
    __builtin_amdgcn_sched_barrier(0);                                                    \
    __builtin_amdgcn_s_barrier();                                                         \
    __builtin_amdgcn_sched_barrier(0);                                                    \
    const char* rb_ = lds + (BUF) * 16384;                                                \
    short8 af[4], bfr[4];                                                                 \
    _Pragma("unroll")                                                                     \
    for (int mi = 0; mi < 4; ++mi) {                                                      \
      int row = wm * 64 + mi * 16 + lr;                                                   \
      af[mi] = *(const short8*)(rb_ + row * 64 + ((lg ^ ((row >> 1) & 3)) << 4));         \
    }                                                                                     \
    _Pragma("unroll")                                                                     \
    for (int ni = 0; ni < 4; ++ni) {                                                      \
      int row = wn * 64 + ni * 16 + lr;                                                   \
      bfr[ni] = *(const short8*)(rb_ + 8192 + row * 64 + ((lg ^ ((row >> 1) & 3)) << 4)); \
    }                                                                                     \
    asm volatile("s_waitcnt lgkmcnt(0)" ::: "memory");                                    \
    __builtin_amdgcn_sched_barrier(0);                                                    \
    __builtin_amdgcn_s_barrier();                                                        \
    __builtin_amdgcn_sched_barrier(0);                                                    \
    if (DOSTAGE) GS((U) + 3, BUF);                                                        \
    __builtin_amdgcn_s_setprio(1);                                                        \
    _Pragma("unroll")                                                                     \
    for (int mi = 0; mi < 4; ++mi)                                                        \
      _Pragma("unroll")                                                                   \
      for (int ni = 0; ni < 4; ++ni)                                                      \
        acc[mi][ni] =                                                                     \
            __builtin_amdgcn_mfma_f32_16x16x32_bf16(af[mi], bfr[ni], acc[mi][ni], 0, 0, 0); \
    __builtin_amdgcn_s_setprio(0);                                                        \
  }

__device__ __forceinline__ void gemm_core(const u16* __restrict__ A,
                                          const u16* __restrict__ Bt,
                                          int K, int m0, int n0,
                                          f32x4 (&acc)[4][4], char* lds) {
  const int t = threadIdx.x;
  const int l = t & 63;
  const int w = t >> 6;
  const int wm = w >> 1, wn = w & 1;
  const int lr = l & 15, lg = l >> 4;
  const int r0 = (w << 5) + (l >> 2);
  const int c = (l & 3) ^ ((r0 >> 1) & 3);
  const u16* As = A + (size_t)(m0 + r0) * K + c * 8;
  const u16* Bs = Bt + (size_t)(n0 + r0) * K + c * 8;

  GS(0, 0);
  GS(1, 1);
  GS(2, 2);

#pragma unroll 1
  for (int i = 0; i < 9; ++i) {
    const int u = 3 * i;
    PH(u + 0, 0, true, "8");
    PH(u + 1, 1, true, "8");
    PH(u + 2, 2, true, "8");
  }
  PH(27, 0, true, "8");
  PH(28, 1, true, "8");
  PH(29, 2, false, "8");
  PH(30, 0, false, "4");
  PH(31, 1, false, "0");
}

__global__ __launch_bounds__(256, 3) void k_gemm_out(const u16* __restrict__ ao,
                                                     const u16* __restrict__ woT,
                                                     const float* __restrict__ bias,
                                                     float* __restrict__ out) {
  __shared__ char lds[49152] __attribute__((aligned(128)));
  int n0 = blockIdx.x * 128, m0 = blockIdx.y * 128;
  f32x4 acc[4][4] = {};
  gemm_core(ao, woT, 1024, m0, n0, acc, lds);
  const int l = threadIdx.x & 63, w = threadIdx.x >> 6;
  const int wm = w >> 1, wn = w & 1;
  const int lr = l & 15, lg = l >> 4;
#pragma unroll
  for (int mi = 0; mi < 4; ++mi)
#pragma unroll
    for (int ni = 0; ni < 4; ++ni)
#pragma unroll
      for (int r = 0; r < 4; ++r) {
        int m = m0 + wm * 64 + mi * 16 + lg * 4 + r;
        int n = n0 + wn * 64 + ni * 16 + lr;
        out[(size_t)m * 1024 + n] = acc[mi][ni][r] + bias[n];
      }
}

// ---------------- flash attention v5 (unchanged from R6) ----------------
__global__ __launch_bounds__(512, 4) void k_attn(const u16* __restrict__ Qg,
                                                 const u16* __restrict__ Kg,
                                                 const u16* __restrict__ Vg,
                                                 const uint32_t* __restrict__ maskw,
                                                 u16* __restrict__ AO) {
  __shared__ char lds[65536] __attribute__((aligned(128)));
  const int bid = blockIdx.x;
  const int qt = bid & 15;
  const int hd = (bid >> 4) & 15;
  const int b = bid >> 8;
  const int bh = (b << 4) + hd;
  const int tx = threadIdx.x, l = tx & 63, w = tx >> 6;
  const int wq = w & 3, kvh = w >> 2;
  const int l31 = l & 31, h = l >> 5;
  const int hx4 = (h ^ (l & 7)) << 4;
  const int sc8 = ((l & 7) ^ (l >> 3)) << 3;
  const int lr8 = l >> 3;

  const u16* Qp = Qg + (size_t)bh * 131072;
  const int q = qt * 128 + wq * 32 + l31;
  const int kv0 = kvh << 10;

  const u16* kg = Kg + (size_t)bh * 131072 + (size_t)(kv0 + 16 * wq + lr8) * 64 + sc8;
  const u16* vg = Vg + (size_t)bh * 131072 + (size_t)(16 * wq + lr8) * 2048 + kv0 + sc8;
  const uint2v* mp = (const uint2v*)(maskw + ((size_t)(b << 11) + q) * 64) + (kvh << 4);

  short8 qf[4];
#pragma unroll
  for (int s = 0; s < 4; ++s)
    qf[s] = *(const short8*)(Qp + (size_t)q * 64 + s * 16 + h * 8);

  const short8 ones8 = {0x3F80, 0x3F80, 0x3F80, 0x3F80, 0x3F80, 0x3F80, 0x3F80, 0x3F80};
  f32x16 Oa[2] = {};
  f32x16 acc_l = {};
  char* ldsH = lds + (kvh << 15);

#define STAGE(BSEL, TT)                                       \
  {                                                           \
    char* base_ = ldsH + (BSEL) * 16384 + (wq << 11);         \
    const u16* k_ = kg + ((size_t)(TT) << 12);                \
    const u16* v_ = vg + ((size_t)(TT) << 6);                 \
    gld_lds16(k_, base_);                                     \
    gld_lds16(k_ + 512, base_ + 1024);                        \
    gld_lds16(v_, base_ + 8192);                              \
    gld_lds16(v_ + 16384, base_ + 9216);                      \
  }

  STAGE(0, 0);

#pragma unroll 1
  for (int tt = 0; tt < 16; ++tt) {
    __syncthreads();
    if (tt + 1 < 16) STAGE((tt + 1) & 1, tt + 1);
    const uint2v mm = mp[tt];
    const char* kbase = ldsH + (tt & 1) * 16384 + l31 * 128;
    const char* vbase = kbase + 8192;

    f32x16 sa = {}, sb = {};
    __builtin_amdgcn_s_setprio(1);
#pragma unroll
    for (int s = 0; s < 4; ++s) {
      short8 k0 = *(const short8*)(kbase + ((s << 5) ^ hx4));
      short8 k1 = *(const short8*)(kbase + 4096 + ((s << 5) ^ hx4));
      sa = __builtin_amdgcn_mfma_f32_32x32x16_bf16(k0, qf[s], sa, 0, 0, 0);
      sb = __builtin_amdgcn_mfma_f32_32x32x16_bf16(k1, qf[s], sb, 0, 0, 0);
    }
    __builtin_amdgcn_s_setprio(0);

    const uint32_t zm0 = mm.x >> (4 * h);
    const uint32_t zm1 = mm.y >> (4 * h);
#pragma unroll
    for (int r = 0; r < 16; ++r) {
      const int oc = (r & 3) + 8 * (r >> 2);
      sa[r] = mask_zero(exp2a(sa[r]), zm0, oc);
      sb[r] = mask_zero(exp2a(sb[r]), zm1, oc);
    }

    short8 pf[4];
    pack_frags(sa, pf[0], pf[1]);
    pack_frags(sb, pf[2], pf[3]);

    __builtin_amdgcn_s_setprio(1);
#pragma unroll
    for (int cc = 0; cc < 4; ++cc) {
      short8 v0 = *(const short8*)(vbase + ((cc << 5) ^ hx4));
      short8 v1 = *(const short8*)(vbase + 4096 + ((cc << 5) ^ hx4));
      Oa[0] = __builtin_amdgcn_mfma_f32_32x32x16_bf16(v0, pf[cc], Oa[0], 0, 0, 0);
      Oa[1] = __builtin_amdgcn_mfma_f32_32x32x16_bf16(v1, pf[cc], Oa[1], 0, 0, 0);
      acc_l = __builtin_amdgcn_mfma_f32_32x32x16_bf16(ones8, pf[cc], acc_l, 0, 0, 0);
    }
    __builtin_amdgcn_s_setprio(0);
  }
#undef STAGE

  __syncthreads();
  float* cb = (float*)lds;
  if (kvh) {
#pragma unroll
    for (int r = 0; r < 32; ++r)
      cb[((wq << 5) + r) * 64 + l] = Oa[r >> 4][r & 15];
    cb[8192 + (wq << 6) + l] = acc_l[0];
  }
  __syncthreads();
  if (!kvh) {
#pragma unroll
    for (int r = 0; r < 32; ++r)
      Oa[r >> 4][r & 15] += cb[((wq << 5) + r) * 64 + l];
    float lt = acc_l[0] + cb[8192 + (wq << 6) + l];
    float inv = 1.0f / fmaxf(lt, 1e-30f);
    u16* orow = AO + ((size_t)(b << 11) + q) * 1024 + hd * 64 + h * 4;
#pragma unroll
    for (int dt = 0; dt < 2; ++dt)
#pragma unroll
      for (int rq = 0; rq < 4; ++rq) {
        uint32_t w0 = cvtpk(Oa[dt][4 * rq + 0] * inv, Oa[dt][4 * rq + 1] * inv);
        uint32_t w1 = cvtpk(Oa[dt][4 * rq + 2] * inv, Oa[dt][4 * rq + 3] * inv);
        *(uint32_t*)(orow + dt * 32 + rq * 8) = w0;
        *(uint32_t*)(orow + dt * 32 + rq * 8 + 2) = w1;
      }
  }
}

// ---------------- launch ----------------

extern "C" void kernel_launch(void* const* d_in, const int* in_sizes, int n_in,
                              void* d_out, int out_size, void* d_ws, size_t ws_size,
                              hipStream_t stream) {
  const float* x = (const float*)d_in[0];
  const int* mask = (const int*)d_in[1];
  const float* Wqkv = (const float*)d_in[2];
  const float* Wout = (const float*)d_in[3];
  const float* bout = (const float*)d_in[4];
  float* out = (float*)d_out;
  char* ws = (char*)d_ws;
  const size_t MB = 1u << 20;
  if (ws_size < 49 * MB) return;

  u16* xb = (u16*)(ws);                     // 8 MB  [4096][1024]
  u16* wqT = (u16*)(ws + 8 * MB);           // 6 MB  [3072][1024]
  u16* woT = (u16*)(ws + 14 * MB);          // 2 MB  [1024][1024]
  uint32_t* mw = (uint32_t*)(ws + 16 * MB); // 1 MB  [B][2048][64]
  u16* Qb = (u16*)(ws + 17 * MB);           // 8 MB  [B,H,2048,64]
  u16* Kb = (u16*)(ws + 25 * MB);           // 8 MB  [B,H,2048,64]
  u16* VT = (u16*)(ws + 33 * MB);           // 8 MB  [B,H,64,2048]
  u16* AO = (u16*)(ws + 41 * MB);           // 8 MB  [4096][1024]

  k_cvt_x<<<4096, 256, 0, stream>>>(x, xb, 1048576);
  k_transpose_bf<<<dim3(96, 32), dim3(32, 8), 0, stream>>>(Wqkv, wqT, 1024, 3072);
  k_transpose_bf<<<dim3(32, 32), dim3(32, 8), 0, stream>>>(Wout, woT, 1024, 1024);
  k_mask_pack<<<32768, 256, 0, stream>>>(mask, mw, 8388608);
  k_gemm_qkv<<<dim3(12, 16), 512, 0, stream>>>(xb, wqT, Qb, Kb, VT);
  k_attn<<<512, 512, 0, stream>>>(Qb, Kb, VT, mw, AO);
  k_gemm_out<<<dim3(8, 32), 256, 0, stream>>>(AO, woT, bout, out);
}

// Round 8
// 129.181 us; speedup vs baseline: 1.2488x; 1.2488x over previous
//
#include <hip/hip_runtime.h>
#include <stdint.h>

typedef unsigned short u16;
typedef short short8 __attribute__((ext_vector_type(8)));
typedef float f32x4 __attribute__((ext_vector_type(4)));
typedef float f32x16 __attribute__((ext_vector_type(16)));
typedef unsigned int uint2v __attribute__((ext_vector_type(2)));

#define K2E 0.18033688011112042f  /* 0.125 * log2(e) */

__device__ __forceinline__ u16 f2bf(float f) {
  union { float f; uint32_t u; } v;
  v.f = f;
  uint32_t u = v.u;
  u += 0x7FFFu + ((u >> 16) & 1u);
  return (u16)(u >> 16);
}

__device__ __forceinline__ uint32_t cvtpk(float lo, float hi) {
  uint32_t r;
  asm("v_cvt_pk_bf16_f32 %0, %1, %2" : "=v"(r) : "v"(lo), "v"(hi));
  return r;
}

__device__ __forceinline__ float exp2a(float x) {
  float r;
  asm("v_exp_f32 %0, %1" : "=v"(r) : "v"(x));
  return r;
}

__device__ __forceinline__ float mask_zero(float p, uint32_t zm, int oc) {
  int mext = __builtin_amdgcn_sbfe((int)zm, oc, 1);
  float r;
  asm("v_bfi_b32 %0, %1, 0, %2" : "=v"(r) : "v"(mext), "v"(p));
  return r;
}

__device__ __forceinline__ void gld_lds16(const u16* src, char* dst) {
  __builtin_amdgcn_global_load_lds((const __attribute__((address_space(1))) void*)src,
                                   (__attribute__((address_space(3))) void*)dst, 16, 0, 0);
}

__device__ __forceinline__ void pack_frags(const f32x16& v, short8& fa, short8& fb) {
  union U { uint32_t w[4]; short8 v8; };
  uint32_t X0 = cvtpk(v[0], v[1]),   X1 = cvtpk(v[2], v[3]);
  uint32_t Y0 = cvtpk(v[4], v[5]),   Y1 = cvtpk(v[6], v[7]);
  uint32_t X2 = cvtpk(v[8], v[9]),   X3 = cvtpk(v[10], v[11]);
  uint32_t Y2 = cvtpk(v[12], v[13]), Y3 = cvtpk(v[14], v[15]);
  uint2v r0 = __builtin_amdgcn_permlane32_swap(X0, Y0, false, false);
  uint2v r1 = __builtin_amdgcn_permlane32_swap(X1, Y1, false, false);
  uint2v r2 = __builtin_amdgcn_permlane32_swap(X2, Y2, false, false);
  uint2v r3 = __builtin_amdgcn_permlane32_swap(X3, Y3, false, false);
  U ua; ua.w[0] = r0.x; ua.w[1] = r1.x; ua.w[2] = r0.y; ua.w[3] = r1.y; fa = ua.v8;
  U ub; ub.w[0] = r2.x; ub.w[1] = r3.x; ub.w[2] = r2.y; ub.w[3] = r3.y; fb = ub.v8;
}

// ---------------- fused prep kernel ----------------
// blocks [0,4096): x -> bf16 ; [4096,7168): Wqkv^T ; [7168,8192): Wout^T ;
// [8192,40960): mask bit-pack. Branches are block-uniform.
__global__ __launch_bounds__(256) void k_prep(const float* __restrict__ x,
                                              u16* __restrict__ xb,
                                              const float* __restrict__ Wqkv,
                                              u16* __restrict__ wqT,
                                              const float* __restrict__ Wout,
                                              u16* __restrict__ woT,
                                              const int* __restrict__ m,
                                              uint32_t* __restrict__ mw) {
  __shared__ float tsh[32][33];
  const int bid = blockIdx.x;
  const int t = threadIdx.x;
  if (bid < 4096) {
    int g = bid * 256 + t;
    float4 v = ((const float4*)x)[g];
    ushort4 o;
    o.x = f2bf(v.x); o.y = f2bf(v.y); o.z = f2bf(v.z); o.w = f2bf(v.w);
    ((ushort4*)xb)[g] = o;
  } else if (bid < 8192) {
    const float* src; u16* dst; int R, C, bb;
    if (bid < 7168) { src = Wqkv; dst = wqT; R = 1024; C = 3072; bb = bid - 4096;
    } else           { src = Wout; dst = woT; R = 1024; C = 1024; bb = bid - 7168; }
    const int nbx = C >> 5;
    const int c0 = (bb % nbx) * 32, r0 = (bb / nbx) * 32;
    const int tx = t & 31, ty = t >> 5;
#pragma unroll
    for (int i = 0; i < 4; ++i)
      tsh[ty + 8 * i][tx] = src[(size_t)(r0 + ty + 8 * i) * C + c0 + tx];
    __syncthreads();
#pragma unroll
    for (int i = 0; i < 4; ++i)
      dst[(size_t)(c0 + ty + 8 * i) * R + r0 + tx] = f2bf(tsh[tx][ty + 8 * i]);
  } else {
    int g = (bid - 8192) * 256 + t;
    unsigned long long bal = __ballot(m[g] != 0);
    int lane = t & 63;
    if (lane == 0) mw[g >> 5] = (uint32_t)bal;
    else if (lane == 32) mw[g >> 5] = (uint32_t)(bal >> 32);
  }
}

// ---------------- GEMM core: 3-deep LDS ring, counted vmcnt (R6, verified) ----------------

#define GS(U, BUF)                                                   \
  {                                                                  \
    char* dA_ = lds + (BUF) * 16384 + (w << 11);                     \
    const u16* a_ = As + ((U) << 5);                                 \
    const u16* b_ = Bs + ((U) << 5);                                 \
    gld_lds16(a_, dA_);                                              \
    gld_lds16(a_ + (K << 4), dA_ + 1024);                            \
    gld_lds16(b_, dA_ + 8192);                                       \
    gld_lds16(b_ + (K << 4), dA_ + 9216);                            \
  }

#define PH(U, BUF, DOSTAGE, VMS)                                                          \
  {                                                                                       \
    asm volatile("s_waitcnt vmcnt(" VMS ")" ::: "memory");                                \
    __builtin_amdgcn_sched_barrier(0);                                                    \
    __builtin_amdgcn_s_barrier();                                                         \
    __builtin_amdgcn_sched_barrier(0);                                                    \
    const char* rb_ = lds + (BUF) * 16384;                                                \
    short8 af[4], bfr[4];                                                                 \
    _Pragma("unroll")                                                                     \
    for (int mi = 0; mi < 4; ++mi) {                                                      \
      int row = wm * 64 + mi * 16 + lr;                                                   \
      af[mi] = *(const short8*)(rb_ + row * 64 + ((lg ^ ((row >> 1) & 3)) << 4));         \
    }                                                                                     \
    _Pragma("unroll")                                                                     \
    for (int ni = 0; ni < 4; ++ni) {                                                      \
      int row = wn * 64 + ni * 16 + lr;                                                   \
      bfr[ni] = *(const short8*)(rb_ + 8192 + row * 64 + ((lg ^ ((row >> 1) & 3)) << 4)); \
    }                                                                                     \
    asm volatile("s_waitcnt lgkmcnt(0)" ::: "memory");                                    \
    __builtin_amdgcn_sched_barrier(0);                                                    \
    __builtin_amdgcn_s_barrier();                                                         \
    __builtin_amdgcn_sched_barrier(0);                                                    \
    if (DOSTAGE) GS((U) + 3, BUF);                                                        \
    __builtin_amdgcn_s_setprio(1);                                                        \
    _Pragma("unroll")                                                                     \
    for (int mi = 0; mi < 4; ++mi)                                                        \
      _Pragma("unroll")                                                                   \
      for (int ni = 0; ni < 4; ++ni)                                                      \
        acc[mi][ni] =                                                                     \
            __builtin_amdgcn_mfma_f32_16x16x32_bf16(af[mi], bfr[ni], acc[mi][ni], 0, 0, 0); \
    __builtin_amdgcn_s_setprio(0);                                                        \
  }

__device__ __forceinline__ void gemm_core(const u16* __restrict__ A,
                                          const u16* __restrict__ Bt,
                                          int K, int m0, int n0,
                                          f32x4 (&acc)[4][4], char* lds) {
  const int t = threadIdx.x;
  const int l = t & 63;
  const int w = t >> 6;
  const int wm = w >> 1, wn = w & 1;
  const int lr = l & 15, lg = l >> 4;
  const int r0 = (w << 5) + (l >> 2);
  const int c = (l & 3) ^ ((r0 >> 1) & 3);
  const u16* As = A + (size_t)(m0 + r0) * K + c * 8;
  const u16* Bs = Bt + (size_t)(n0 + r0) * K + c * 8;

  GS(0, 0);
  GS(1, 1);
  GS(2, 2);

#pragma unroll 1
  for (int i = 0; i < 9; ++i) {
    const int u = 3 * i;
    PH(u + 0, 0, true, "8");
    PH(u + 1, 1, true, "8");
    PH(u + 2, 2, true, "8");
  }
  PH(27, 0, true, "8");
  PH(28, 1, true, "8");
  PH(29, 2, false, "8");
  PH(30, 0, false, "4");
  PH(31, 1, false, "0");
}

// grid 768 flat; XCD-bijective swizzle (768 % 8 == 0): work chunked per XCD.
__global__ __launch_bounds__(256, 3) void k_gemm_qkv(const u16* __restrict__ xb,
                                                     const u16* __restrict__ wqT,
                                                     u16* __restrict__ Qb,
                                                     u16* __restrict__ Kb,
                                                     u16* __restrict__ VT) {
  __shared__ char lds[49152] __attribute__((aligned(128)));
  const int bid = blockIdx.x;
  const int wg = (bid & 7) * 96 + (bid >> 3);
  const int m0 = (wg / 24) * 128, n0 = (wg % 24) * 128;
  f32x4 acc[4][4] = {};
  gemm_core(xb, wqT, 1024, m0, n0, acc, lds);
  const int l = threadIdx.x & 63, w = threadIdx.x >> 6;
  const int wm = w >> 1, wn = w & 1;
  const int lr = l & 15, lg = l >> 4;
#pragma unroll
  for (int mi = 0; mi < 4; ++mi)
#pragma unroll
    for (int ni = 0; ni < 4; ++ni)
#pragma unroll
      for (int r = 0; r < 4; ++r) {
        int m = m0 + wm * 64 + mi * 16 + lg * 4 + r;
        int n = n0 + wn * 64 + ni * 16 + lr;
        int b = m >> 11, seq = m & 2047;
        float av = acc[mi][ni][r];
        if (n < 1024) {
          Qb[((size_t)((b << 4) + (n >> 6)) * 2048 + seq) * 64 + (n & 63)] = f2bf(av * K2E);
        } else if (n < 2048) {
          int nn = n - 1024;
          Kb[((size_t)((b << 4) + (nn >> 6)) * 2048 + seq) * 64 + (nn & 63)] = f2bf(av);
        } else {
          int nn = n - 2048;
          VT[((size_t)((b << 4) + (nn >> 6)) * 64 + (nn & 63)) * 2048 + seq] = f2bf(av);
        }
      }
}

// grid 256 flat; XCD swizzle.
__global__ __launch_bounds__(256, 3) void k_gemm_out(const u16* __restrict__ ao,
                                                     const u16* __restrict__ woT,
                                                     const float* __restrict__ bias,
                                                     float* __restrict__ out) {
  __shared__ char lds[49152] __attribute__((aligned(128)));
  const int bid = blockIdx.x;
  const int wg = (bid & 7) * 32 + (bid >> 3);
  const int m0 = (wg >> 3) * 128, n0 = (wg & 7) * 128;
  f32x4 acc[4][4] = {};
  gemm_core(ao, woT, 1024, m0, n0, acc, lds);
  const int l = threadIdx.x & 63, w = threadIdx.x >> 6;
  const int wm = w >> 1, wn = w & 1;
  const int lr = l & 15, lg = l >> 4;
#pragma unroll
  for (int mi = 0; mi < 4; ++mi)
#pragma unroll
    for (int ni = 0; ni < 4; ++ni)
#pragma unroll
      for (int r = 0; r < 4; ++r) {
        int m = m0 + wm * 64 + mi * 16 + lg * 4 + r;
        int n = n0 + wn * 64 + ni * 16 + lr;
        out[(size_t)m * 1024 + n] = acc[mi][ni][r] + bias[n];
      }
}

// ---------------- flash attention v5 (R6 core) + XCD swizzle ----------------
__global__ __launch_bounds__(512, 4) void k_attn(const u16* __restrict__ Qg,
                                                 const u16* __restrict__ Kg,
                                                 const u16* __restrict__ Vg,
                                                 const uint32_t* __restrict__ maskw,
                                                 u16* __restrict__ AO) {
  __shared__ char lds[65536] __attribute__((aligned(128)));
  const int bid0 = blockIdx.x;
  const int bid = (bid0 & 7) * 64 + (bid0 >> 3);  // XCD chunk swizzle (512 % 8 == 0)
  const int qt = bid & 15;
  const int hd = (bid >> 4) & 15;
  const int b = bid >> 8;
  const int bh = (b << 4) + hd;
  const int tx = threadIdx.x, l = tx & 63, w = tx >> 6;
  const int wq = w & 3, kvh = w >> 2;
  const int l31 = l & 31, h = l >> 5;
  const int hx4 = (h ^ (l & 7)) << 4;
  const int sc8 = ((l & 7) ^ (l >> 3)) << 3;
  const int lr8 = l >> 3;

  const u16* Qp = Qg + (size_t)bh * 131072;
  const int q = qt * 128 + wq * 32 + l31;
  const int kv0 = kvh << 10;

  const u16* kg = Kg + (size_t)bh * 131072 + (size_t)(kv0 + 16 * wq + lr8) * 64 + sc8;
  const u16* vg = Vg + (size_t)bh * 131072 + (size_t)(16 * wq + lr8) * 2048 + kv0 + sc8;
  const uint2v* mp = (const uint2v*)(maskw + ((size_t)(b << 11) + q) * 64) + (kvh << 4);

  short8 qf[4];
#pragma unroll
  for (int s = 0; s < 4; ++s)
    qf[s] = *(const short8*)(Qp + (size_t)q * 64 + s * 16 + h * 8);

  const short8 ones8 = {0x3F80, 0x3F80, 0x3F80, 0x3F80, 0x3F80, 0x3F80, 0x3F80, 0x3F80};
  f32x16 Oa[2] = {};
  f32x16 acc_l = {};
  char* ldsH = lds + (kvh << 15);

#define STAGE(BSEL, TT)                                       \
  {                                                           \
    char* base_ = ldsH + (BSEL) * 16384 + (wq << 11);         \
    const u16* k_ = kg + ((size_t)(TT) << 12);                \
    const u16* v_ = vg + ((size_t)(TT) << 6);                 \
    gld_lds16(k_, base_);                                     \
    gld_lds16(k_ + 512, base_ + 1024);                        \
    gld_lds16(v_, base_ + 8192);                              \
    gld_lds16(v_ + 16384, base_ + 9216);                      \
  }

  STAGE(0, 0);

#pragma unroll 1
  for (int tt = 0; tt < 16; ++tt) {
    __syncthreads();
    if (tt + 1 < 16) STAGE((tt + 1) & 1, tt + 1);
    const uint2v mm = mp[tt];
    const char* kbase = ldsH + (tt & 1) * 16384 + l31 * 128;
    const char* vbase = kbase + 8192;

    f32x16 sa = {}, sb = {};
    __builtin_amdgcn_s_setprio(1);
#pragma unroll
    for (int s = 0; s < 4; ++s) {
      short8 k0 = *(const short8*)(kbase + ((s << 5) ^ hx4));
      short8 k1 = *(const short8*)(kbase + 4096 + ((s << 5) ^ hx4));
      sa = __builtin_amdgcn_mfma_f32_32x32x16_bf16(k0, qf[s], sa, 0, 0, 0);
      sb = __builtin_amdgcn_mfma_f32_32x32x16_bf16(k1, qf[s], sb, 0, 0, 0);
    }
    __builtin_amdgcn_s_setprio(0);

    const uint32_t zm0 = mm.x >> (4 * h);
    const uint32_t zm1 = mm.y >> (4 * h);
#pragma unroll
    for (int r = 0; r < 16; ++r) {
      const int oc = (r & 3) + 8 * (r >> 2);
      sa[r] = mask_zero(exp2a(sa[r]), zm0, oc);
      sb[r] = mask_zero(exp2a(sb[r]), zm1, oc);
    }

    short8 pf[4];
    pack_frags(sa, pf[0], pf[1]);
    pack_frags(sb, pf[2], pf[3]);

    __builtin_amdgcn_s_setprio(1);
#pragma unroll
    for (int cc = 0; cc < 4; ++cc) {
      short8 v0 = *(const short8*)(vbase + ((cc << 5) ^ hx4));
      short8 v1 = *(const short8*)(vbase + 4096 + ((cc << 5) ^ hx4));
      Oa[0] = __builtin_amdgcn_mfma_f32_32x32x16_bf16(v0, pf[cc], Oa[0], 0, 0, 0);
      Oa[1] = __builtin_amdgcn_mfma_f32_32x32x16_bf16(v1, pf[cc], Oa[1], 0, 0, 0);
      acc_l = __builtin_amdgcn_mfma_f32_32x32x16_bf16(ones8, pf[cc], acc_l, 0, 0, 0);
    }
    __builtin_amdgcn_s_setprio(0);
  }
#undef STAGE

  __syncthreads();
  float* cb = (float*)lds;
  if (kvh) {
#pragma unroll
    for (int r = 0; r < 32; ++r)
      cb[((wq << 5) + r) * 64 + l] = Oa[r >> 4][r & 15];
    cb[8192 + (wq << 6) + l] = acc_l[0];
  }
  __syncthreads();
  if (!kvh) {
#pragma unroll
    for (int r = 0; r < 32; ++r)
      Oa[r >> 4][r & 15] += cb[((wq << 5) + r) * 64 + l];
    float lt = acc_l[0] + cb[8192 + (wq << 6) + l];
    float inv = 1.0f / fmaxf(lt, 1e-30f);
    u16* orow = AO + ((size_t)(b << 11) + q) * 1024 + hd * 64 + h * 4;
#pragma unroll
    for (int dt = 0; dt < 2; ++dt)
#pragma unroll
      for (int rq = 0; rq < 4; ++rq) {
        uint32_t w0 = cvtpk(Oa[dt][4 * rq + 0] * inv, Oa[dt][4 * rq + 1] * inv);
        uint32_t w1 = cvtpk(Oa[dt][4 * rq + 2] * inv, Oa[dt][4 * rq + 3] * inv);
        *(uint32_t*)(orow + dt * 32 + rq * 8) = w0;
        *(uint32_t*)(orow + dt * 32 + rq * 8 + 2) = w1;
      }
  }
}

// ---------------- launch ----------------

extern "C" void kernel_launch(void* const* d_in, const int* in_sizes, int n_in,
                              void* d_out, int out_size, void* d_ws, size_t ws_size,
                              hipStream_t stream) {
  const float* x = (const float*)d_in[0];
  const int* mask = (const int*)d_in[1];
  const float* Wqkv = (const float*)d_in[2];
  const float* Wout = (const float*)d_in[3];
  const float* bout = (const float*)d_in[4];
  float* out = (float*)d_out;
  char* ws = (char*)d_ws;
  const size_t MB = 1u << 20;
  if (ws_size < 49 * MB) return;

  u16* xb = (u16*)(ws);                     // 8 MB  [4096][1024]
  u16* wqT = (u16*)(ws + 8 * MB);           // 6 MB  [3072][1024]
  u16* woT = (u16*)(ws + 14 * MB);          // 2 MB  [1024][1024]
  uint32_t* mw = (uint32_t*)(ws + 16 * MB); // 1 MB  [B][2048][64]
  u16* Qb = (u16*)(ws + 17 * MB);           // 8 MB  [B,H,2048,64]
  u16* Kb = (u16*)(ws + 25 * MB);           // 8 MB  [B,H,2048,64]
  u16* VT = (u16*)(ws + 33 * MB);           // 8 MB  [B,H,64,2048]
  u16* AO = (u16*)(ws + 41 * MB);           // 8 MB  [4096][1024]

  k_prep<<<40960, 256, 0, stream>>>(x, xb, Wqkv, wqT, Wout, woT, mask, mw);
  k_gemm_qkv<<<768, 256, 0, stream>>>(xb, wqT, Qb, Kb, VT);
  k_attn<<<512, 512, 0, stream>>>(Qb, Kb, VT, mw, AO);
  k_gemm_out<<<256, 256, 0, stream>>>(AO, woT, bout, out);
}

// Round 10
// 125.522 us; speedup vs baseline: 1.2852x; 1.0292x over previous
//
#include <hip/hip_runtime.h>
#include <stdint.h>

typedef unsigned short u16;
typedef short short8 __attribute__((ext_vector_type(8)));
typedef float f32x4 __attribute__((ext_vector_type(4)));
typedef float f32x16 __attribute__((ext_vector_type(16)));
typedef unsigned int uint2v __attribute__((ext_vector_type(2)));

#define K2E 0.18033688011112042f  /* 0.125 * log2(e) */

__device__ __forceinline__ u16 f2bf(float f) {
  union { float f; uint32_t u; } v;
  v.f = f;
  uint32_t u = v.u;
  u += 0x7FFFu + ((u >> 16) & 1u);
  return (u16)(u >> 16);
}

__device__ __forceinline__ uint32_t cvtpk(float lo, float hi) {
  uint32_t r;
  asm("v_cvt_pk_bf16_f32 %0, %1, %2" : "=v"(r) : "v"(lo), "v"(hi));
  return r;
}

__device__ __forceinline__ float exp2a(float x) {
  float r;
  asm("v_exp_f32 %0, %1" : "=v"(r) : "v"(x));
  return r;
}

__device__ __forceinline__ float mask_zero(float p, uint32_t zm, int oc) {
  int mext = __builtin_amdgcn_sbfe((int)zm, oc, 1);
  float r;
  asm("v_bfi_b32 %0, %1, 0, %2" : "=v"(r) : "v"(mext), "v"(p));
  return r;
}

__device__ __forceinline__ void gld_lds16(const u16* src, char* dst) {
  __builtin_amdgcn_global_load_lds((const __attribute__((address_space(1))) void*)src,
                                   (__attribute__((address_space(3))) void*)dst, 16, 0, 0);
}

__device__ __forceinline__ void pack_frags(const f32x16& v, short8& fa, short8& fb) {
  union U { uint32_t w[4]; short8 v8; };
  uint32_t X0 = cvtpk(v[0], v[1]),   X1 = cvtpk(v[2], v[3]);
  uint32_t Y0 = cvtpk(v[4], v[5]),   Y1 = cvtpk(v[6], v[7]);
  uint32_t X2 = cvtpk(v[8], v[9]),   X3 = cvtpk(v[10], v[11]);
  uint32_t Y2 = cvtpk(v[12], v[13]), Y3 = cvtpk(v[14], v[15]);
  uint2v r0 = __builtin_amdgcn_permlane32_swap(X0, Y0, false, false);
  uint2v r1 = __builtin_amdgcn_permlane32_swap(X1, Y1, false, false);
  uint2v r2 = __builtin_amdgcn_permlane32_swap(X2, Y2, false, false);
  uint2v r3 = __builtin_amdgcn_permlane32_swap(X3, Y3, false, false);
  U ua; ua.w[0] = r0.x; ua.w[1] = r1.x; ua.w[2] = r0.y; ua.w[3] = r1.y; fa = ua.v8;
  U ub; ub.w[0] = r2.x; ub.w[1] = r3.x; ub.w[2] = r2.y; ub.w[3] = r3.y; fb = ub.v8;
}

// ---------------- fused prep kernel (R8, verified) ----------------
__global__ __launch_bounds__(256) void k_prep(const float* __restrict__ x,
                                              u16* __restrict__ xb,
                                              const float* __restrict__ Wqkv,
                                              u16* __restrict__ wqT,
                                              const float* __restrict__ Wout,
                                              u16* __restrict__ woT,
                                              const int* __restrict__ m,
                                              uint32_t* __restrict__ mw) {
  __shared__ float tsh[32][33];
  const int bid = blockIdx.x;
  const int t = threadIdx.x;
  if (bid < 4096) {
    int g = bid * 256 + t;
    float4 v = ((const float4*)x)[g];
    ushort4 o;
    o.x = f2bf(v.x); o.y = f2bf(v.y); o.z = f2bf(v.z); o.w = f2bf(v.w);
    ((ushort4*)xb)[g] = o;
  } else if (bid < 8192) {
    const float* src; u16* dst; int R, C, bb;
    if (bid < 7168) { src = Wqkv; dst = wqT; R = 1024; C = 3072; bb = bid - 4096;
    } else           { src = Wout; dst = woT; R = 1024; C = 1024; bb = bid - 7168; }
    const int nbx = C >> 5;
    const int c0 = (bb % nbx) * 32, r0 = (bb / nbx) * 32;
    const int tx = t & 31, ty = t >> 5;
#pragma unroll
    for (int i = 0; i < 4; ++i)
      tsh[ty + 8 * i][tx] = src[(size_t)(r0 + ty + 8 * i) * C + c0 + tx];
    __syncthreads();
#pragma unroll
    for (int i = 0; i < 4; ++i)
      dst[(size_t)(c0 + ty + 8 * i) * R + r0 + tx] = f2bf(tsh[tx][ty + 8 * i]);
  } else {
    int g = (bid - 8192) * 256 + t;
    unsigned long long bal = __ballot(m[g] != 0);
    int lane = t & 63;
    if (lane == 0) mw[g >> 5] = (uint32_t)bal;
    else if (lane == 32) mw[g >> 5] = (uint32_t)(bal >> 32);
  }
}

// ---------------- GEMM core: 3-deep LDS ring (128x128, R6 verified) ----------------

#define GS(U, BUF)                                                   \
  {                                                                  \
    char* dA_ = lds + (BUF) * 16384 + (w << 11);                     \
    const u16* a_ = As + ((U) << 5);                                 \
    const u16* b_ = Bs + ((U) << 5);                                 \
    gld_lds16(a_, dA_);                                              \
    gld_lds16(a_ + (K << 4), dA_ + 1024);                            \
    gld_lds16(b_, dA_ + 8192);                                       \
    gld_lds16(b_ + (K << 4), dA_ + 9216);                            \
  }

#define PH(U, BUF, DOSTAGE, VMS)                                                          \
  {                                                                                       \
    asm volatile("s_waitcnt vmcnt(" VMS ")" ::: "memory");                                \
    __builtin_amdgcn_sched_barrier(0);                                                    \
    __builtin_amdgcn_s_barrier();                                                         \
    __builtin_amdgcn_sched_barrier(0);                                                    \
    const char* rb_ = lds + (BUF) * 16384;                                                \
    short8 af[4], bfr[4];                                                                 \
    _Pragma("unroll")                                                                     \
    for (int mi = 0; mi < 4; ++mi) {                                                      \
      int row = wm * 64 + mi * 16 + lr;                                                   \
      af[mi] = *(const short8*)(rb_ + row * 64 + ((lg ^ ((row >> 1) & 3)) << 4));         \
    }                                                                                     \
    _Pragma("unroll")                                                                     \
    for (int ni = 0; ni < 4; ++ni) {                                                      \
      int row = wn * 64 + ni * 16 + lr;                                                   \
      bfr[ni] = *(const short8*)(rb_ + 8192 + row * 64 + ((lg ^ ((row >> 1) & 3)) << 4)); \
    }                                                                                     \
    asm volatile("s_waitcnt lgkmcnt(0)" ::: "memory");                                    \
    __builtin_amdgcn_sched_barrier(0);                                                    \
    __builtin_amdgcn_s_barrier();                                                        \
    __builtin_amdgcn_sched_barrier(0);                                                    \
    if (DOSTAGE) GS((U) + 3, BUF);                                                        \
    __builtin_amdgcn_s_setprio(1);                                                        \
    _Pragma("unroll")                                                                     \
    for (int mi = 0; mi < 4; ++mi)                                                        \
      _Pragma("unroll")                                                                   \
      for (int ni = 0; ni < 4; ++ni)                                                      \
        acc[mi][ni] =                                                                     \
            __builtin_amdgcn_mfma_f32_16x16x32_bf16(af[mi], bfr[ni], acc[mi][ni], 0, 0, 0); \
    __builtin_amdgcn_s_setprio(0);                                                        \
  }

__device__ __forceinline__ void gemm_core(const u16* __restrict__ A,
                                          const u16* __restrict__ Bt,
                                          int K, int m0, int n0,
                                          f32x4 (&acc)[4][4], char* lds) {
  const int t = threadIdx.x;
  const int l = t & 63;
  const int w = t >> 6;
  const int wm = w >> 1, wn = w & 1;
  const int lr = l & 15, lg = l >> 4;
  const int r0 = (w << 5) + (l >> 2);
  const int c = (l & 3) ^ ((r0 >> 1) & 3);
  const u16* As = A + (size_t)(m0 + r0) * K + c * 8;
  const u16* Bs = Bt + (size_t)(n0 + r0) * K + c * 8;

  GS(0, 0);
  GS(1, 1);
  GS(2, 2);

#pragma unroll 1
  for (int i = 0; i < 9; ++i) {
    const int u = 3 * i;
    PH(u + 0, 0, true, "8");
    PH(u + 1, 1, true, "8");
    PH(u + 2, 2, true, "8");
  }
  PH(27, 0, true, "8");
  PH(28, 1, true, "8");
  PH(29, 2, false, "8");
  PH(30, 0, false, "4");
  PH(31, 1, false, "0");
}

// grid 768 flat; XCD swizzle. V-tile blocks (n0>=2048) transpose via LDS.
__global__ __launch_bounds__(256, 3) void k_gemm_qkv(const u16* __restrict__ xb,
                                                     const u16* __restrict__ wqT,
                                                     u16* __restrict__ Qb,
                                                     u16* __restrict__ Kb,
                                                     u16* __restrict__ VT) {
  __shared__ char lds[49152] __attribute__((aligned(128)));
  const int bid = blockIdx.x;
  const int wg = (bid & 7) * 96 + (bid >> 3);
  const int m0 = (wg / 24) * 128, n0 = (wg % 24) * 128;
  f32x4 acc[4][4] = {};
  gemm_core(xb, wqT, 1024, m0, n0, acc, lds);
  const int l = threadIdx.x & 63, w = threadIdx.x >> 6;
  const int wm = w >> 1, wn = w & 1;
  const int lr = l & 15, lg = l >> 4;
  const int b = m0 >> 11;
  if (n0 >= 2048) {
    // all-V block: LDS transpose -> coalesced VT row writes
    __syncthreads();
    u16* lt = (u16*)lds;  // [128][136] u16 (272B pitch: 8-way bank spread)
#pragma unroll
    for (int mi = 0; mi < 4; ++mi)
#pragma unroll
      for (int ni = 0; ni < 4; ++ni)
#pragma unroll
        for (int r = 0; r < 4; ++r) {
          int ml = wm * 64 + mi * 16 + lg * 4 + r;
          int nl = wn * 64 + ni * 16 + lr;
          lt[nl * 136 + ml] = f2bf(acc[mi][ni][r]);
        }
    __syncthreads();
    const int nl = threadIdx.x >> 1, hf = threadIdx.x & 1;
    const int nn = n0 - 2048 + nl;
    const int seq = (m0 & 2047) + hf * 64;
    u16* dst = VT + ((size_t)((b << 4) + (nn >> 6)) * 64 + (nn & 63)) * 2048 + seq;
    const u16* srcr = lt + nl * 136 + hf * 64;
#pragma unroll
    for (int i = 0; i < 8; ++i)
      *(uint4*)(dst + i * 8) = *(const uint4*)(srcr + i * 8);
  } else {
#pragma unroll
    for (int mi = 0; mi < 4; ++mi)
#pragma unroll
      for (int ni = 0; ni < 4; ++ni)
#pragma unroll
        for (int r = 0; r < 4; ++r) {
          int m = m0 + wm * 64 + mi * 16 + lg * 4 + r;
          int n = n0 + wn * 64 + ni * 16 + lr;
          int seq = m & 2047;
          float av = acc[mi][ni][r];
          if (n < 1024) {
            Qb[((size_t)((b << 4) + (n >> 6)) * 2048 + seq) * 64 + (n & 63)] = f2bf(av * K2E);
          } else {
            int nn = n - 1024;
            Kb[((size_t)((b << 4) + (nn >> 6)) * 2048 + seq) * 64 + (nn & 63)] = f2bf(av);
          }
        }
  }
}

// ---------------- GEMM 64x128 3-ring (gemm_out): 512 blocks ----------------
// unit = A(64x32k = 4KB) + B(128x32k = 8KB) = 12KB; ring3 = 36KB; 3 loads/unit
// -> steady vmcnt(6); tail 6/3/0. B second load = rows +64 -> offset (K<<6). [R9 fix]

#define OGS(U, BUF)                                                  \
  {                                                                  \
    char* d_ = lds + (BUF) * 12288 + (w << 10);                      \
    const u16* a_ = As + ((U) << 5);                                 \
    const u16* b_ = Bs + ((U) << 5);                                 \
    gld_lds16(a_, d_);                                               \
    gld_lds16(b_, d_ + 4096);                                        \
    gld_lds16(b_ + (K << 6), d_ + 8192);                             \
  }

#define OPH(U, BUF, DOSTAGE, VMS)                                                         \
  {                                                                                       \
    asm volatile("s_waitcnt vmcnt(" VMS ")" ::: "memory");                                \
    __builtin_amdgcn_sched_barrier(0);                                                    \
    __builtin_amdgcn_s_barrier();                                                         \
    __builtin_amdgcn_sched_barrier(0);                                                    \
    const char* rb_ = lds + (BUF) * 12288;                                                \
    short8 af[2], bfr[4];                                                                 \
    _Pragma("unroll")                                                                     \
    for (int mi = 0; mi < 2; ++mi) {                                                      \
      int row = wm * 32 + mi * 16 + lr;                                                   \
      af[mi] = *(const short8*)(rb_ + row * 64 + ((lg ^ ((row >> 1) & 3)) << 4));         \
    }                                                                                     \
    _Pragma("unroll")                                                                     \
    for (int ni = 0; ni < 4; ++ni) {                                                      \
      int row = wn * 64 + ni * 16 + lr;                                                   \
      bfr[ni] = *(const short8*)(rb_ + 4096 + row * 64 + ((lg ^ ((row >> 1) & 3)) << 4)); \
    }                                                                                     \
    asm volatile("s_waitcnt lgkmcnt(0)" ::: "memory");                                    \
    __builtin_amdgcn_sched_barrier(0);                                                    \
    __builtin_amdgcn_s_barrier();                                                        \
    __builtin_amdgcn_sched_barrier(0);                                                    \
    if (DOSTAGE) OGS((U) + 3, BUF);                                                       \
    __builtin_amdgcn_s_setprio(1);                                                        \
    _Pragma("unroll")                                                                     \
    for (int mi = 0; mi < 2; ++mi)                                                        \
      _Pragma("unroll")                                                                   \
      for (int ni = 0; ni < 4; ++ni)                                                      \
        acc[mi][ni] =                                                                     \
            __builtin_amdgcn_mfma_f32_16x16x32_bf16(af[mi], bfr[ni], acc[mi][ni], 0, 0, 0); \
    __builtin_amdgcn_s_setprio(0);                                                        \
  }

__global__ __launch_bounds__(256, 4) void k_gemm_out(const u16* __restrict__ ao,
                                                     const u16* __restrict__ woT,
                                                     const float* __restrict__ bias,
                                                     float* __restrict__ out) {
  __shared__ char lds[36864] __attribute__((aligned(128)));
  const int K = 1024;
  const int bid = blockIdx.x;
  const int wg = (bid & 7) * 64 + (bid >> 3);
  const int m0 = (wg >> 3) * 64, n0 = (wg & 7) * 128;
  const int t = threadIdx.x;
  const int l = t & 63;
  const int w = t >> 6;
  const int wm = w >> 1, wn = w & 1;
  const int lr = l & 15, lg = l >> 4;
  const int sr = (w << 4) + (l >> 2);
  const int sc = (l & 3) ^ ((sr >> 1) & 3);
  const u16* As = ao + (size_t)(m0 + sr) * K + sc * 8;
  const u16* Bs = woT + (size_t)(n0 + sr) * K + sc * 8;

  f32x4 acc[2][4] = {};

  OGS(0, 0);
  OGS(1, 1);
  OGS(2, 2);

#pragma unroll 1
  for (int i = 0; i < 9; ++i) {
    const int u = 3 * i;
    OPH(u + 0, 0, true, "6");
    OPH(u + 1, 1, true, "6");
    OPH(u + 2, 2, true, "6");
  }
  OPH(27, 0, true, "6");
  OPH(28, 1, true, "6");
  OPH(29, 2, false, "6");
  OPH(30, 0, false, "3");
  OPH(31, 1, false, "0");

#pragma unroll
  for (int mi = 0; mi < 2; ++mi)
#pragma unroll
    for (int ni = 0; ni < 4; ++ni)
#pragma unroll
      for (int r = 0; r < 4; ++r) {
        int m = m0 + wm * 32 + mi * 16 + lg * 4 + r;
        int n = n0 + wn * 64 + ni * 16 + lr;
        out[(size_t)m * 1024 + n] = acc[mi][ni][r] + bias[n];
      }
}

// ---------------- flash attention v5 + XCD swizzle (R8, verified) ----------------
__global__ __launch_bounds__(512, 4) void k_attn(const u16* __restrict__ Qg,
                                                 const u16* __restrict__ Kg,
                                                 const u16* __restrict__ Vg,
                                                 const uint32_t* __restrict__ maskw,
                                                 u16* __restrict__ AO) {
  __shared__ char lds[65536] __attribute__((aligned(128)));
  const int bid0 = blockIdx.x;
  const int bid = (bid0 & 7) * 64 + (bid0 >> 3);
  const int qt = bid & 15;
  const int hd = (bid >> 4) & 15;
  const int b = bid >> 8;
  const int bh = (b << 4) + hd;
  const int tx = threadIdx.x, l = tx & 63, w = tx >> 6;
  const int wq = w & 3, kvh = w >> 2;
  const int l31 = l & 31, h = l >> 5;
  const int hx4 = (h ^ (l & 7)) << 4;
  const int sc8 = ((l & 7) ^ (l >> 3)) << 3;
  const int lr8 = l >> 3;

  const u16* Qp = Qg + (size_t)bh * 131072;
  const int q = qt * 128 + wq * 32 + l31;
  const int kv0 = kvh << 10;

  const u16* kg = Kg + (size_t)bh * 131072 + (size_t)(kv0 + 16 * wq + lr8) * 64 + sc8;
  const u16* vg = Vg + (size_t)bh * 131072 + (size_t)(16 * wq + lr8) * 2048 + kv0 + sc8;
  const uint2v* mp = (const uint2v*)(maskw + ((size_t)(b << 11) + q) * 64) + (kvh << 4);

  short8 qf[4];
#pragma unroll
  for (int s = 0; s < 4; ++s)
    qf[s] = *(const short8*)(Qp + (size_t)q * 64 + s * 16 + h * 8);

  const short8 ones8 = {0x3F80, 0x3F80, 0x3F80, 0x3F80, 0x3F80, 0x3F80, 0x3F80, 0x3F80};
  f32x16 Oa[2] = {};
  f32x16 acc_l = {};
  char* ldsH = lds + (kvh << 15);

#define STAGE(BSEL, TT)                                       \
  {                                                           \
    char* base_ = ldsH + (BSEL) * 16384 + (wq << 11);         \
    const u16* k_ = kg + ((size_t)(TT) << 12);                \
    const u16* v_ = vg + ((size_t)(TT) << 6);                 \
    gld_lds16(k_, base_);                                     \
    gld_lds16(k_ + 512, base_ + 1024);                        \
    gld_lds16(v_, base_ + 8192);                              \
    gld_lds16(v_ + 16384, base_ + 9216);                      \
  }

  STAGE(0, 0);

#pragma unroll 1
  for (int tt = 0; tt < 16; ++tt) {
    __syncthreads();
    if (tt + 1 < 16) STAGE((tt + 1) & 1, tt + 1);
    const uint2v mm = mp[tt];
    const char* kbase = ldsH + (tt & 1) * 16384 + l31 * 128;
    const char* vbase = kbase + 8192;

    f32x16 sa = {}, sb = {};
    __builtin_amdgcn_s_setprio(1);
#pragma unroll
    for (int s = 0; s < 4; ++s) {
      short8 k0 = *(const short8*)(kbase + ((s << 5) ^ hx4));
      short8 k1 = *(const short8*)(kbase + 4096 + ((s << 5) ^ hx4));
      sa = __builtin_amdgcn_mfma_f32_32x32x16_bf16(k0, qf[s], sa, 0, 0, 0);
      sb = __builtin_amdgcn_mfma_f32_32x32x16_bf16(k1, qf[s], sb, 0, 0, 0);
    }
    __builtin_amdgcn_s_setprio(0);

    const uint32_t zm0 = mm.x >> (4 * h);
    const uint32_t zm1 = mm.y >> (4 * h);
#pragma unroll
    for (int r = 0; r < 16; ++r) {
      const int oc = (r & 3) + 8 * (r >> 2);
      sa[r] = mask_zero(exp2a(sa[r]), zm0, oc);
      sb[r] = mask_zero(exp2a(sb[r]), zm1, oc);
    }

    short8 pf[4];
    pack_frags(sa, pf[0], pf[1]);
    pack_frags(sb, pf[2], pf[3]);

    __builtin_amdgcn_s_setprio(1);
#pragma unroll
    for (int cc = 0; cc < 4; ++cc) {
      short8 v0 = *(const short8*)(vbase + ((cc << 5) ^ hx4));
      short8 v1 = *(const short8*)(vbase + 4096 + ((cc << 5) ^ hx4));
      Oa[0] = __builtin_amdgcn_mfma_f32_32x32x16_bf16(v0, pf[cc], Oa[0], 0, 0, 0);
      Oa[1] = __builtin_amdgcn_mfma_f32_32x32x16_bf16(v1, pf[cc], Oa[1], 0, 0, 0);
      acc_l = __builtin_amdgcn_mfma_f32_32x32x16_bf16(ones8, pf[cc], acc_l, 0, 0, 0);
    }
    __builtin_amdgcn_s_setprio(0);
  }
#undef STAGE

  __syncthreads();
  float* cb = (float*)lds;
  if (kvh) {
#pragma unroll
    for (int r = 0; r < 32; ++r)
      cb[((wq << 5) + r) * 64 + l] = Oa[r >> 4][r & 15];
    cb[8192 + (wq << 6) + l] = acc_l[0];
  }
  __syncthreads();
  if (!kvh) {
#pragma unroll
    for (int r = 0; r < 32; ++r)
      Oa[r >> 4][r & 15] += cb[((wq << 5) + r) * 64 + l];
    float lt = acc_l[0] + cb[8192 + (wq << 6) + l];
    float inv = 1.0f / fmaxf(lt, 1e-30f);
    u16* orow = AO + ((size_t)(b << 11) + q) * 1024 + hd * 64 + h * 4;
#pragma unroll
    for (int dt = 0; dt < 2; ++dt)
#pragma unroll
      for (int rq = 0; rq < 4; ++rq) {
        uint32_t w0 = cvtpk(Oa[dt][4 * rq + 0] * inv, Oa[dt][4 * rq + 1] * inv);
        uint32_t w1 = cvtpk(Oa[dt][4 * rq + 2] * inv, Oa[dt][4 * rq + 3] * inv);
        *(uint32_t*)(orow + dt * 32 + rq * 8) = w0;
        *(uint32_t*)(orow + dt * 32 + rq * 8 + 2) = w1;
      }
  }
}

// ---------------- launch ----------------

extern "C" void kernel_launch(void* const* d_in, const int* in_sizes, int n_in,
                              void* d_out, int out_size, void* d_ws, size_t ws_size,
                              hipStream_t stream) {
  const float* x = (const float*)d_in[0];
  const int* mask = (const int*)d_in[1];
  const float* Wqkv = (const float*)d_in[2];
  const float* Wout = (const float*)d_in[3];
  const float* bout = (const float*)d_in[4];
  float* out = (float*)d_out;
  char* ws = (char*)d_ws;
  const size_t MB = 1u << 20;
  if (ws_size < 49 * MB) return;

  u16* xb = (u16*)(ws);                     // 8 MB  [4096][1024]
  u16* wqT = (u16*)(ws + 8 * MB);           // 6 MB  [3072][1024]
  u16* woT = (u16*)(ws + 14 * MB);          // 2 MB  [1024][1024]
  uint32_t* mw = (uint32_t*)(ws + 16 * MB); // 1 MB  [B][2048][64]
  u16* Qb = (u16*)(ws + 17 * MB);           // 8 MB  [B,H,2048,64]
  u16* Kb = (u16*)(ws + 25 * MB);           // 8 MB  [B,H,2048,64]
  u16* VT = (u16*)(ws + 33 * MB);           // 8 MB  [B,H,64,2048]
  u16* AO = (u16*)(ws + 41 * MB);           // 8 MB  [4096][1024]

  k_prep<<<40960, 256, 0, stream>>>(x, xb, Wqkv, wqT, Wout, woT, mask, mw);
  k_gemm_qkv<<<768, 256, 0, stream>>>(xb, wqT, Qb, Kb, VT);
  k_attn<<<512, 512, 0, stream>>>(Qb, Kb, VT, mw, AO);
  k_gemm_out<<<512, 256, 0, stream>>>(AO, woT, bout, out);
}